// Round 1
// baseline (503.794 us; speedup 1.0000x reference)
//
#include <hip/hip_runtime.h>

#define N_NODES 100000
#define N_EDGES 1000000
#define D 64
#define SCAN_BLK 98   // ceil(100000/1024)

// ---------------- CSR build ----------------

__global__ void k_zero_deg(int* deg) {
    int i = blockIdx.x * blockDim.x + threadIdx.x;
    if (i < N_NODES) deg[i] = 0;
}

__global__ void k_hist(const int* __restrict__ ei, int* __restrict__ deg) {
    int e = blockIdx.x * blockDim.x + threadIdx.x;
    if (e < N_EDGES) atomicAdd(&deg[ei[N_EDGES + e]], 1);
}

// phase 1: per-block (1024 elems) sums
__global__ void k_blocksum(const int* __restrict__ deg, int* __restrict__ bsum) {
    __shared__ int sdata[256];
    int t = threadIdx.x, b = blockIdx.x;
    int base = b * 1024 + t * 4;
    int s = 0;
#pragma unroll
    for (int i = 0; i < 4; i++) {
        int idx = base + i;
        if (idx < N_NODES) s += deg[idx];
    }
    sdata[t] = s;
    __syncthreads();
    for (int off = 128; off > 0; off >>= 1) {
        if (t < off) sdata[t] += sdata[t + off];
        __syncthreads();
    }
    if (t == 0) bsum[b] = sdata[0];
}

// phase 2: single small block scans the 98 block sums (exclusive, in place)
__global__ void k_scan_bsum(int* __restrict__ bsum, int nb, int* __restrict__ row_start) {
    __shared__ int tmp[128];
    int t = threadIdx.x;
    int v = (t < nb) ? bsum[t] : 0;
    tmp[t] = v;
    __syncthreads();
    for (int off = 1; off < 128; off <<= 1) {
        int add = (t >= off) ? tmp[t - off] : 0;
        __syncthreads();
        tmp[t] += add;
        __syncthreads();
    }
    int total = tmp[127];
    int excl = (t == 0) ? 0 : tmp[t - 1];
    if (t < nb) bsum[t] = excl;
    if (t == 0) row_start[N_NODES] = total;
}

// phase 3: per-block exclusive scan + offset; writes row_start, cursor, inv_cnt
__global__ void k_scan_write(const int* __restrict__ deg, const int* __restrict__ bsum,
                             int* __restrict__ row_start, int* __restrict__ cursor,
                             float* __restrict__ inv_cnt) {
    __shared__ int tmp[256];
    int t = threadIdx.x, b = blockIdx.x;
    int base = b * 1024 + t * 4;
    int local[4];
    int s = 0;
#pragma unroll
    for (int i = 0; i < 4; i++) {
        int idx = base + i;
        int d = (idx < N_NODES) ? deg[idx] : 0;
        local[i] = d;
        s += d;
    }
    tmp[t] = s;
    __syncthreads();
    for (int off = 1; off < 256; off <<= 1) {
        int add = (t >= off) ? tmp[t - off] : 0;
        __syncthreads();
        tmp[t] += add;
        __syncthreads();
    }
    int run = bsum[b] + ((t == 0) ? 0 : tmp[t - 1]);
#pragma unroll
    for (int i = 0; i < 4; i++) {
        int idx = base + i;
        if (idx < N_NODES) {
            row_start[idx] = run;
            cursor[idx] = run;
            int d = local[i];
            inv_cnt[idx] = 1.0f / (float)(d > 0 ? d : 1);
            run += d;
        }
    }
}

__global__ void k_scatter(const int* __restrict__ ei, int* __restrict__ cursor,
                          int* __restrict__ col) {
    int e = blockIdx.x * blockDim.x + threadIdx.x;
    if (e < N_EDGES) {
        int s = ei[e];
        int d = ei[N_EDGES + e];
        int p = atomicAdd(&cursor[d], 1);
        col[p] = s;
    }
}

// ---------------- aggregation: mean over in-neighbors ----------------
// wave per node, lane = feature; each neighbor row read is a coalesced 256B load
__global__ void k_agg(const float* __restrict__ X, const int* __restrict__ row_start,
                      const int* __restrict__ col, const float* __restrict__ inv_cnt,
                      float* __restrict__ M) {
    int lane = threadIdx.x & 63;
    int wid = (blockIdx.x * blockDim.x + threadIdx.x) >> 6;
    int nw = (gridDim.x * blockDim.x) >> 6;
    for (int n = wid; n < N_NODES; n += nw) {
        int s = row_start[n];
        int e = row_start[n + 1];
        float acc = 0.f;
        for (int j = s; j < e; j++) {
            acc += X[(size_t)col[j] * D + lane];
        }
        M[(size_t)n * D + lane] = acc * inv_cnt[n];
    }
}

// ---------------- fused linear: out = M*Wl^T + X*Wr^T + b (opt relu) -------------
__device__ __forceinline__ float bcast(float v, int l) {
    return __int_as_float(__builtin_amdgcn_readlane(__float_as_int(v), l));
}

__global__ void __launch_bounds__(256, 2)
k_linear(const float* __restrict__ Ma, const float* __restrict__ Xa,
         const float* __restrict__ Wl, const float* __restrict__ Wr,
         const float* __restrict__ bias, float* __restrict__ out, int do_relu) {
    int lane = threadIdx.x & 63;
    // per-lane weight rows: lane o holds Wl[o][*], Wr[o][*] in VGPRs
    float wl[D], wr[D];
    const float4* Wl4 = (const float4*)Wl;
    const float4* Wr4 = (const float4*)Wr;
#pragma unroll
    for (int k4 = 0; k4 < D / 4; k4++) {
        float4 a = Wl4[lane * (D / 4) + k4];
        wl[k4 * 4 + 0] = a.x; wl[k4 * 4 + 1] = a.y;
        wl[k4 * 4 + 2] = a.z; wl[k4 * 4 + 3] = a.w;
        float4 bq = Wr4[lane * (D / 4) + k4];
        wr[k4 * 4 + 0] = bq.x; wr[k4 * 4 + 1] = bq.y;
        wr[k4 * 4 + 2] = bq.z; wr[k4 * 4 + 3] = bq.w;
    }
    float bv = bias[lane];
    int wid = (blockIdx.x * blockDim.x + threadIdx.x) >> 6;
    int nw = (gridDim.x * blockDim.x) >> 6;
    for (int n = wid; n < N_NODES; n += nw) {
        float a0 = Ma[(size_t)n * D + lane];
        float a1 = Xa[(size_t)n * D + lane];
        float acc0 = 0.f, acc1 = 0.f, acc2 = 0.f, acc3 = 0.f;
#pragma unroll
        for (int k = 0; k < D; k += 2) {
            acc0 = fmaf(bcast(a0, k), wl[k], acc0);
            acc1 = fmaf(bcast(a1, k), wr[k], acc1);
            acc2 = fmaf(bcast(a0, k + 1), wl[k + 1], acc2);
            acc3 = fmaf(bcast(a1, k + 1), wr[k + 1], acc3);
        }
        float r = bv + (acc0 + acc2) + (acc1 + acc3);
        if (do_relu) r = fmaxf(r, 0.f);
        out[(size_t)n * D + lane] = r;
    }
}

// ---------------- launch ----------------
extern "C" void kernel_launch(void* const* d_in, const int* in_sizes, int n_in,
                              void* d_out, int out_size, void* d_ws, size_t ws_size,
                              hipStream_t stream) {
    const float* x   = (const float*)d_in[0];
    const int*   ei  = (const int*)d_in[1];
    const float* W1l = (const float*)d_in[2];
    const float* b1  = (const float*)d_in[3];
    const float* W1r = (const float*)d_in[4];
    const float* W2l = (const float*)d_in[5];
    const float* b2  = (const float*)d_in[6];
    const float* W2r = (const float*)d_in[7];
    float* out = (float*)d_out;

    char* ws = (char*)d_ws;
    size_t off = 0;
    auto alloc = [&](size_t bytes) -> char* {
        char* p = ws + off;
        off = (off + bytes + 255) & ~(size_t)255;
        return p;
    };
    int*   deg       = (int*)alloc((size_t)N_NODES * 4);
    int*   row_start = (int*)alloc((size_t)(N_NODES + 1) * 4);
    int*   cursor    = (int*)alloc((size_t)N_NODES * 4);
    int*   col       = (int*)alloc((size_t)N_EDGES * 4);
    float* invc      = (float*)alloc((size_t)N_NODES * 4);
    int*   bsum      = (int*)alloc(128 * 4);
    float* mbuf      = (float*)alloc((size_t)N_NODES * D * 4);
    float* hbuf      = (float*)alloc((size_t)N_NODES * D * 4);

    // CSR build (once; reused by both layers)
    k_zero_deg<<<(N_NODES + 255) / 256, 256, 0, stream>>>(deg);
    k_hist<<<(N_EDGES + 255) / 256, 256, 0, stream>>>(ei, deg);
    k_blocksum<<<SCAN_BLK, 256, 0, stream>>>(deg, bsum);
    k_scan_bsum<<<1, 128, 0, stream>>>(bsum, SCAN_BLK, row_start);
    k_scan_write<<<SCAN_BLK, 256, 0, stream>>>(deg, bsum, row_start, cursor, invc);
    k_scatter<<<(N_EDGES + 255) / 256, 256, 0, stream>>>(ei, cursor, col);

    // layer 1
    k_agg<<<2048, 256, 0, stream>>>(x, row_start, col, invc, mbuf);
    k_linear<<<1024, 256, 0, stream>>>(mbuf, x, W1l, W1r, b1, hbuf, 1);
    // layer 2
    k_agg<<<2048, 256, 0, stream>>>(hbuf, row_start, col, invc, mbuf);
    k_linear<<<1024, 256, 0, stream>>>(mbuf, hbuf, W2l, W2r, b2, out, 0);
}